// Round 2
// baseline (137.828 us; speedup 1.0000x reference)
//
#include <hip/hip_runtime.h>

#define VIEWN 360
#define NDETC 736
#define HWPIX 102400     // 320*320
#define NP2   2048
#define VC    8          // view chunks for backprojection
#define VPC   45         // views per chunk (8*45 = 360)

// ---------------------------------------------------------------------------
// Kernel A: g[m] = (DELTA_S/2048) * sum_j RF[j]*win[j]*cos(2*pi*j*m/2048)
// This is DELTA_S * Re(ifft(recon_filter*window)) — the spatial ramp kernel.
// real(ifft(fft(p)*RF)) == p (circ-conv) Re(ifft(RF)) for real p, real-even RF.
// ---------------------------------------------------------------------------
__global__ __launch_bounds__(256) void build_g_kernel(
    const float* __restrict__ rf, const float* __restrict__ win,
    float* __restrict__ g)
{
    __shared__ double red[256];
    const int m = blockIdx.x;          // 0..2047
    const int tid = threadIdx.x;
    double acc = 0.0;
    for (int j = tid; j < NP2; j += 256) {
        const int r = (j * m) & (NP2 - 1);               // (j*m) mod 2048, exact
        const float c = cospif((float)r * (1.0f / 1024.0f)); // cos(2*pi*r/2048)
        acc += (double)(rf[j] * win[j]) * (double)c;
    }
    red[tid] = acc;
    __syncthreads();
    for (int s = 128; s > 0; s >>= 1) {
        if (tid < s) red[tid] += red[tid + s];
        __syncthreads();
    }
    if (tid == 0) g[m] = (float)(red[0] * (0.5 / 2048.0)); // DELTA_S=0.5 folded
}

// ---------------------------------------------------------------------------
// Kernel B: filt[v][d] = sum_{k=0}^{735} sino[v][k]*cw[k] * g[d+735-k]
// (index range [0,1470] — no wraparound needed)
// ---------------------------------------------------------------------------
__global__ __launch_bounds__(256) void filter_kernel(
    const float* __restrict__ sino, const float* __restrict__ cw,
    const float* __restrict__ g, float* __restrict__ filt)
{
    __shared__ float ws[NDETC];
    __shared__ float gs[NP2];
    const int v = blockIdx.x;
    const int tid = threadIdx.x;
    for (int k = tid; k < NDETC; k += 256)
        ws[k] = sino[v * NDETC + k] * cw[k];
    for (int j = tid; j < NP2; j += 256)
        gs[j] = g[j];
    __syncthreads();
    for (int d = tid; d < NDETC; d += 256) {
        float acc = 0.0f;
        const float* gp = &gs[d + NDETC - 1];
        #pragma unroll 4
        for (int k = 0; k < NDETC; ++k)
            acc = fmaf(ws[k], gp[-k], acc);
        filt[v * NDETC + d] = acc;
    }
}

// ---------------------------------------------------------------------------
// Kernel T: iy depends only on the view (view_xy_n is tiled) — 360-entry table.
// STRICT f32 chain (numpy keeps f32 under NEP-50 scalar promotion);
// __float2int_rn = round-half-to-even, matches np.round.
// ---------------------------------------------------------------------------
__global__ void iy_table_kernel(const float* __restrict__ grid, int* __restrict__ iy_tab)
{
    const int v = blockIdx.x * 64 + threadIdx.x;
    if (v < VIEWN) {
        const float gy = grid[(size_t)v * HWPIX * 2 + 1];   // gy of pixel 0 (all equal)
        float t = __fadd_rn(gy, 1.0f);
        t = __fmul_rn(t, 360.0f);
        t = __fadd_rn(t, -1.0f);
        t = __fmul_rn(t, 0.5f);          // /2.0 exact
        iy_tab[v] = __float2int_rn(t);
    }
}

// ---------------------------------------------------------------------------
// Kernel C: backprojection. Memory-bound: streams grid (295MB) + square (147MB).
// grid split over (pixel-block, view-chunk); deterministic partial sums in ws.
// ix computed in STRICT f32 (uncontracted __f*_rn) to match the np reference's
// nearest-neighbor index decisions bit-exactly.
// ---------------------------------------------------------------------------
__global__ __launch_bounds__(256) void backproject_kernel(
    const float* __restrict__ grid, const float* __restrict__ square,
    const float* __restrict__ filt, const int* __restrict__ iy_tab,
    float* __restrict__ partial)
{
    const int p = blockIdx.x * 256 + threadIdx.x;
    const int c = blockIdx.y;
    const int v0 = c * VPC;
    const float2* gp = reinterpret_cast<const float2*>(grid) + (size_t)v0 * HWPIX + p;
    const float*  sp = square + (size_t)v0 * HWPIX + p;
    float acc = 0.0f;
    for (int v = 0; v < VPC; ++v) {
        const float2 g2 = *gp;
        const float  sq = *sp;
        gp += HWPIX; sp += HWPIX;
        const int iy = iy_tab[v0 + v];                    // uniform -> scalar load
        // tx = ((gx+1)*736 - 1)/2 in strict f32 (matches numpy op-by-op, no FMA)
        float tx = __fadd_rn(g2.x, 1.0f);
        tx = __fmul_rn(tx, 736.0f);
        tx = __fadd_rn(tx, -1.0f);
        tx = __fmul_rn(tx, 0.5f);
        const int ix = __float2int_rn(tx);                // round half-to-even
        const bool valid = (ix >= 0) & (ix < NDETC) & (iy >= 0) & (iy < VIEWN);
        const int ixc = min(max(ix, 0), NDETC - 1);
        const int iyc = min(max(iy, 0), VIEWN - 1);
        const float val = valid ? filt[iyc * NDETC + ixc] : 0.0f;
        acc += val * __builtin_amdgcn_rcpf(sq);           // sq in [0.25,2.3]; ~1ulp rcp
    }
    partial[(size_t)c * HWPIX + p] = acc;
}

// ---------------------------------------------------------------------------
// Kernel D: out[p] = D_BETA * sum_c partial[c][p] * mask[p]
// ---------------------------------------------------------------------------
__global__ __launch_bounds__(256) void reduce_kernel(
    const float* __restrict__ partial, const float* __restrict__ mask,
    float* __restrict__ out)
{
    const int p = blockIdx.x * 256 + threadIdx.x;
    float s = 0.0f;
    #pragma unroll
    for (int c = 0; c < VC; ++c)
        s += partial[(size_t)c * HWPIX + p];
    out[p] = (float)(0.017453292519943295 * (double)s * (double)mask[p]); // D_BETA = pi/180
}

extern "C" void kernel_launch(void* const* d_in, const int* in_sizes, int n_in,
                              void* d_out, int out_size, void* d_ws, size_t ws_size,
                              hipStream_t stream)
{
    (void)in_sizes; (void)n_in; (void)out_size; (void)ws_size;
    const float* sino   = (const float*)d_in[0];
    const float* cw     = (const float*)d_in[1];
    const float* rf     = (const float*)d_in[2];
    const float* win    = (const float*)d_in[3];
    const float* grid   = (const float*)d_in[4];
    const float* square = (const float*)d_in[5];
    const float* mask   = (const float*)d_in[6];
    float* out = (float*)d_out;

    // ws layout: g[2048] f32 | filt[360*736] f32 | partial[8*102400] f32 | iy_tab[360] i32
    char* ws = (char*)d_ws;
    float* g       = (float*)(ws);
    float* filt    = (float*)(ws + 8192);
    float* partial = (float*)(ws + 8192 + (size_t)VIEWN * NDETC * 4);            // 1,068,032
    int*   iy_tab  = (int*)  (ws + 8192 + (size_t)VIEWN * NDETC * 4
                                 + (size_t)VC * HWPIX * 4);                      // 4,344,832

    build_g_kernel<<<NP2, 256, 0, stream>>>(rf, win, g);
    iy_table_kernel<<<(VIEWN + 63) / 64, 64, 0, stream>>>(grid, iy_tab);
    filter_kernel<<<VIEWN, 256, 0, stream>>>(sino, cw, g, filt);
    backproject_kernel<<<dim3(HWPIX / 256, VC), 256, 0, stream>>>(grid, square, filt, iy_tab, partial);
    reduce_kernel<<<HWPIX / 256, 256, 0, stream>>>(partial, mask, out);
}

// Round 3
// 78.341 us; speedup vs baseline: 1.7593x; 1.7593x over previous
//
#include <hip/hip_runtime.h>

#define VIEWN 360
#define NDETC 736
#define HWPIX 102400     // 320*320
#define NP2   2048
#define VC    8          // view chunks for backprojection
#define VPC   45         // views per chunk (8*45 = 360)

// ---------------------------------------------------------------------------
// Kernel A: g[m] = (DELTA_S/2048) * sum_j RF[j]*win[j]*cos(2*pi*j*m/2048)
// = DELTA_S * Re(ifft(recon_filter*window)); filtering is then a circular
// convolution, realized as a 736-tap linear conv (no wraparound in the crop).
// ---------------------------------------------------------------------------
__global__ __launch_bounds__(256) void build_g_kernel(
    const float* __restrict__ rf, const float* __restrict__ win,
    float* __restrict__ g)
{
    __shared__ double red[256];
    const int m = blockIdx.x;          // 0..2047
    const int tid = threadIdx.x;
    double acc = 0.0;
    for (int j = tid; j < NP2; j += 256) {
        const int r = (j * m) & (NP2 - 1);               // (j*m) mod 2048, exact
        const float c = cospif((float)r * (1.0f / 1024.0f)); // cos(2*pi*r/2048)
        acc += (double)(rf[j] * win[j]) * (double)c;
    }
    red[tid] = acc;
    __syncthreads();
    for (int s = 128; s > 0; s >>= 1) {
        if (tid < s) red[tid] += red[tid + s];
        __syncthreads();
    }
    if (tid == 0) g[m] = (float)(red[0] * (0.5 / 2048.0)); // DELTA_S=0.5 folded
}

// ---------------------------------------------------------------------------
// Kernel T: per-view table: sin/cos(beta) in f64 (replicating np.linspace's
// step rounding) + iy from the actual grid input (strict f32, round-half-even
// == np.round). iy depends only on the view (view_xy_n is tiled).
// ---------------------------------------------------------------------------
__global__ __launch_bounds__(64) void view_tab_kernel(
    const float* __restrict__ grid, double* __restrict__ sbcb,
    int* __restrict__ iy_tab)
{
    const int v = blockIdx.x * 64 + threadIdx.x;
    if (v >= VIEWN) return;
    // D_BETA exactly as the host computes it: ((pi*360)/360)/180, each op rounded
    const double db   = ((3.141592653589793 * 360.0) / 360.0) / 180.0;
    const double stop = 359.0 * db;            // (VIEW-1)*D_BETA
    const double step = stop / 359.0;          // np.linspace internal step
    const double beta = (v == 359) ? stop : (double)v * step; // endpoint forced
    sbcb[2 * v]     = sin(beta);
    sbcb[2 * v + 1] = cos(beta);
    const float gy = grid[(size_t)v * HWPIX * 2 + 1];   // gy of pixel 0 (all equal)
    float t = __fadd_rn(gy, 1.0f);
    t = __fmul_rn(t, 360.0f);
    t = __fadd_rn(t, -1.0f);
    t = __fmul_rn(t, 0.5f);
    iy_tab[v] = __float2int_rn(t);
}

// ---------------------------------------------------------------------------
// Kernel B: filt[v][d] = sum_{k=0}^{735} sino[v][k]*cw[k] * g[d+735-k]
// Split over 3 d-blocks per view for occupancy (1080 blocks).
// ---------------------------------------------------------------------------
__global__ __launch_bounds__(256) void filter_kernel(
    const float* __restrict__ sino, const float* __restrict__ cw,
    const float* __restrict__ g, float* __restrict__ filt)
{
    __shared__ float ws[NDETC];
    __shared__ float gs[992];
    const int v   = blockIdx.x;
    const int d0  = blockIdx.y * 256;
    const int tid = threadIdx.x;
    for (int k = tid; k < NDETC; k += 256)
        ws[k] = sino[v * NDETC + k] * cw[k];
    for (int m = tid; m < 991; m += 256)
        gs[m] = g[d0 + m];                 // max idx d0+990 = 1502 < 2048
    __syncthreads();
    const int d = d0 + tid;
    if (d < NDETC) {
        float acc = 0.0f;
        const float* gp = &gs[tid + NDETC - 1];
        #pragma unroll 8
        for (int k = 0; k < NDETC; ++k)
            acc = fmaf(ws[k], gp[-k], acc);
        filt[v * NDETC + d] = acc;
    }
}

// ---------------------------------------------------------------------------
// Kernel C: backprojection with ON-THE-FLY geometry (no grid/square reads).
// x_j = 1.1*(j-159.5), y_i = 1.1*(i-159.5)  (exact f64)
// r*sin(beta-phi) = sb*x - cb*y ;  r*cos(beta-phi) = cb*x + sb*y
// t = 500 + r*sin(...) ;  gx = (r*cos(...))*(500/183.75)/t ; square = t^2/250000
// gx matches the host's f64 pipeline to ~3-6 ulp -> expected ix flips ~3e-5.
// Index chain then strict f32 (uncontracted) + round-half-even = np.round.
// ---------------------------------------------------------------------------
__global__ __launch_bounds__(256) void backproject_kernel(
    const double* __restrict__ sbcb, const int* __restrict__ iy_tab,
    const float* __restrict__ filt, float* __restrict__ partial)
{
    const int p = blockIdx.x * 256 + threadIdx.x;
    const int c = blockIdx.y;
    const int v0 = c * VPC;
    const int j = p % 320;                  // x index (fast dim)
    const int i = p / 320;                  // y index
    const double xj = ((double)j - 159.5) * 1.1;
    const double yi = ((double)i - 159.5) * 1.1;
    const double CGX = 500.0 / 183.75;      // compile-time f64, correctly rounded
    const double INV = 1.0 / 250000.0;
    float acc = 0.0f;
    #pragma unroll 3
    for (int v = v0; v < v0 + VPC; ++v) {
        const double sb = sbcb[2 * v];
        const double cb = sbcb[2 * v + 1];
        const int iy = iy_tab[v];                       // uniform -> scalar load
        const double rs  = sb * xj - cb * yi;           // r*sin(beta-phi)
        const double num = cb * xj + sb * yi;           // r*cos(beta-phi)
        const double t   = 500.0 + rs;                  // 500*U, t in [252,748]
        const double gxd = num * CGX / t;               // s_xy / 183.75
        const float  gx  = (float)gxd;
        float tx = __fadd_rn(gx, 1.0f);                 // strict f32, no FMA
        tx = __fmul_rn(tx, 736.0f);
        tx = __fadd_rn(tx, -1.0f);
        tx = __fmul_rn(tx, 0.5f);
        const int ix = __float2int_rn(tx);              // round half-to-even
        const bool valid = (ix >= 0) & (ix < NDETC) & (iy >= 0) & (iy < VIEWN);
        const int ixc = min(max(ix, 0), NDETC - 1);
        const int iyc = min(max(iy, 0), VIEWN - 1);
        const float val = valid ? filt[iyc * NDETC + ixc] : 0.0f;
        const float sq  = (float)(t * t * INV);         // U^2, ~1e-7 rel vs host
        acc += val * __builtin_amdgcn_rcpf(sq);         // sq in [0.25,2.3]; ~1ulp
    }
    partial[(size_t)c * HWPIX + p] = acc;
}

// ---------------------------------------------------------------------------
// Kernel D: out[p] = D_BETA * sum_c partial[c][p] * mask[p]
// ---------------------------------------------------------------------------
__global__ __launch_bounds__(256) void reduce_kernel(
    const float* __restrict__ partial, const float* __restrict__ mask,
    float* __restrict__ out)
{
    const int p = blockIdx.x * 256 + threadIdx.x;
    const double db = ((3.141592653589793 * 360.0) / 360.0) / 180.0;
    float s = 0.0f;
    #pragma unroll
    for (int c = 0; c < VC; ++c)
        s += partial[(size_t)c * HWPIX + p];
    out[p] = (float)(db * (double)s * (double)mask[p]);
}

extern "C" void kernel_launch(void* const* d_in, const int* in_sizes, int n_in,
                              void* d_out, int out_size, void* d_ws, size_t ws_size,
                              hipStream_t stream)
{
    (void)in_sizes; (void)n_in; (void)out_size; (void)ws_size;
    const float* sino   = (const float*)d_in[0];
    const float* cw     = (const float*)d_in[1];
    const float* rf     = (const float*)d_in[2];
    const float* win    = (const float*)d_in[3];
    const float* grid   = (const float*)d_in[4];
    const float* mask   = (const float*)d_in[6];
    float* out = (float*)d_out;

    // ws layout: g[2048] | filt[360*736] | partial[8*102400] | iy_tab[360] | sbcb[360*2 f64]
    char* ws = (char*)d_ws;
    float*  g       = (float*)(ws);
    float*  filt    = (float*)(ws + 8192);
    float*  partial = (float*)(ws + 8192 + (size_t)VIEWN * NDETC * 4);          // 1,068,032
    int*    iy_tab  = (int*)  (ws + 8192 + (size_t)VIEWN * NDETC * 4
                                  + (size_t)VC * HWPIX * 4);                    // 4,344,832
    double* sbcb    = (double*)(ws + 4346272);                                  // 8-aligned

    view_tab_kernel<<<(VIEWN + 63) / 64, 64, 0, stream>>>(grid, sbcb, iy_tab);
    build_g_kernel<<<NP2, 256, 0, stream>>>(rf, win, g);
    filter_kernel<<<dim3(VIEWN, 3), 256, 0, stream>>>(sino, cw, g, filt);
    backproject_kernel<<<dim3(HWPIX / 256, VC), 256, 0, stream>>>(sbcb, iy_tab, filt, partial);
    reduce_kernel<<<HWPIX / 256, 256, 0, stream>>>(partial, mask, out);
}

// Round 4
// 68.928 us; speedup vs baseline: 1.9996x; 1.1366x over previous
//
#include <hip/hip_runtime.h>

#define VIEWN 360
#define NDETC 736
#define HWPIX 102400     // 320*320
#define NP2   2048
#define VC    8          // view chunks for backprojection
#define VPC   45         // views per chunk (8*45 = 360)

// ---------------------------------------------------------------------------
// Kernel A (blocks 0..2047): g[m] = (DELTA_S/2048)*sum_j RF[j]*win[j]*cos(2pi j m/2048)
//   = DELTA_S * Re(ifft(recon_filter*window)) — the spatial ramp kernel.
// Block 2048: per-view table — sin/cos(beta) in f64 (replicating np.linspace)
//   + iy from the actual grid input (strict f32 chain, round-half-even).
// ---------------------------------------------------------------------------
__global__ __launch_bounds__(256) void build_g_vt_kernel(
    const float* __restrict__ rf, const float* __restrict__ win,
    const float* __restrict__ grid,
    float* __restrict__ g, double* __restrict__ sbcb, int* __restrict__ iy_tab)
{
    const int tid = threadIdx.x;
    if (blockIdx.x == NP2) {
        for (int v = tid; v < VIEWN; v += 256) {
            const double db   = ((3.141592653589793 * 360.0) / 360.0) / 180.0;
            const double stop = 359.0 * db;            // (VIEW-1)*D_BETA
            const double step = stop / 359.0;          // np.linspace internal step
            const double beta = (v == 359) ? stop : (double)v * step;
            sbcb[2 * v]     = sin(beta);
            sbcb[2 * v + 1] = cos(beta);
            const float gy = grid[(size_t)v * HWPIX * 2 + 1];
            float t = __fadd_rn(gy, 1.0f);
            t = __fmul_rn(t, 360.0f);
            t = __fadd_rn(t, -1.0f);
            t = __fmul_rn(t, 0.5f);
            iy_tab[v] = __float2int_rn(t);
        }
        return;
    }
    __shared__ double red[256];
    const int m = blockIdx.x;
    double acc = 0.0;
    for (int j = tid; j < NP2; j += 256) {
        const int r = (j * m) & (NP2 - 1);               // (j*m) mod 2048, exact
        const float c = cospif((float)r * (1.0f / 1024.0f));
        acc += (double)(rf[j] * win[j]) * (double)c;
    }
    red[tid] = acc;
    __syncthreads();
    for (int s = 128; s > 0; s >>= 1) {
        if (tid < s) red[tid] += red[tid + s];
        __syncthreads();
    }
    if (tid == 0) g[m] = (float)(red[0] * (0.5 / 2048.0)); // DELTA_S=0.5 folded
}

// ---------------------------------------------------------------------------
// Kernel B: filt[v][d] = sum_{k=0}^{735} ws[k] * g[d+735-k], register-tiled:
// each thread computes 4 consecutive d; k unrolled by 4; the 7-value g-window
// lives in registers (1 aligned ds_read_b128 refill + 1 broadcast b128 for ws
// per 16 FMAs). Per-output k-order is ascending — bit-exact vs prior rounds.
// Grid (view, half): d = half*368 + 4*tid, tid<92.
// ---------------------------------------------------------------------------
__global__ __launch_bounds__(128) void filter_kernel(
    const float* __restrict__ sino, const float* __restrict__ cw,
    const float* __restrict__ g, float* __restrict__ filt)
{
    __shared__ __align__(16) float ws[NDETC];
    __shared__ __align__(16) float gs[1472];
    const int v    = blockIdx.x;
    const int half = blockIdx.y;
    const int tid  = threadIdx.x;
    for (int k = tid; k < NDETC; k += 128)
        ws[k] = sino[v * NDETC + k] * cw[k];
    for (int m = tid; m < 1472; m += 128)
        gs[m] = g[m];
    __syncthreads();
    if (tid < 92) {
        const int d = half * 368 + 4 * tid;
        float4 acc = make_float4(0.f, 0.f, 0.f, 0.f);
        float4 p = *(const float4*)&gs[d + 736];         // prologue: win[4..6] seed
        for (int k0 = 0; k0 < NDETC; k0 += 4) {
            const float4 c = *(const float4*)&gs[d + 732 - k0]; // aligned (d,k0 %4==0)
            const float4 w = *(const float4*)&ws[k0];           // wave-uniform
            // window: win[0..3]=c.xyzw, win[4..6]=p.xyz ; acc.j += w[kk]*win[3-kk+j]
            acc.x = fmaf(w.x, c.w, acc.x);
            acc.y = fmaf(w.x, p.x, acc.y);
            acc.z = fmaf(w.x, p.y, acc.z);
            acc.w = fmaf(w.x, p.z, acc.w);
            acc.x = fmaf(w.y, c.z, acc.x);
            acc.y = fmaf(w.y, c.w, acc.y);
            acc.z = fmaf(w.y, p.x, acc.z);
            acc.w = fmaf(w.y, p.y, acc.w);
            acc.x = fmaf(w.z, c.y, acc.x);
            acc.y = fmaf(w.z, c.z, acc.y);
            acc.z = fmaf(w.z, c.w, acc.z);
            acc.w = fmaf(w.z, p.x, acc.w);
            acc.x = fmaf(w.w, c.x, acc.x);
            acc.y = fmaf(w.w, c.y, acc.y);
            acc.z = fmaf(w.w, c.z, acc.z);
            acc.w = fmaf(w.w, c.w, acc.w);
            p = c;
        }
        *(float4*)&filt[v * NDETC + d] = acc;            // 16B-aligned
    }
}

// ---------------------------------------------------------------------------
// Kernel C: backprojection with on-the-fly geometry (no grid/square reads).
// x_j = 1.1*(j-159.5), y_i = 1.1*(i-159.5)  (exact f64)
// rs = sb*x - cb*y ; num = cb*x + sb*y ; t = 500 + rs
// 1/t via f32 rcp + 2 f64 Newton steps (~3 ulp) instead of exact f64 div.
// gx = num*(500/183.75)*(1/t); index chain strict f32 + round-half-even.
// ---------------------------------------------------------------------------
__global__ __launch_bounds__(256) void backproject_kernel(
    const double* __restrict__ sbcb, const int* __restrict__ iy_tab,
    const float* __restrict__ filt, float* __restrict__ partial)
{
    const int p = blockIdx.x * 256 + threadIdx.x;
    const int c = blockIdx.y;
    const int v0 = c * VPC;
    const int j = p % 320;                  // x index (fast dim)
    const int i = p / 320;                  // y index
    const double xj = ((double)j - 159.5) * 1.1;
    const double yi = ((double)i - 159.5) * 1.1;
    const double CGX = 500.0 / 183.75;
    const double INV = 1.0 / 250000.0;
    float acc = 0.0f;
    #pragma unroll 3
    for (int v = v0; v < v0 + VPC; ++v) {
        const double sb = sbcb[2 * v];
        const double cb = sbcb[2 * v + 1];
        const int iy = iy_tab[v];                       // uniform -> scalar load
        const double rs  = sb * xj - cb * yi;           // r*sin(beta-phi)
        const double num = cb * xj + sb * yi;           // r*cos(beta-phi)
        const double t   = 500.0 + rs;                  // 500*U, t in [252,748]
        double r0 = (double)__builtin_amdgcn_rcpf((float)t);
        r0 = r0 * fma(-t, r0, 2.0);                     // Newton 1: ~2^-46
        r0 = r0 * fma(-t, r0, 2.0);                     // Newton 2: ~f64 rounding
        const double gxd = (num * CGX) * r0;
        const float  gx  = (float)gxd;
        float tx = __fadd_rn(gx, 1.0f);                 // strict f32, no FMA
        tx = __fmul_rn(tx, 736.0f);
        tx = __fadd_rn(tx, -1.0f);
        tx = __fmul_rn(tx, 0.5f);
        const int ix = __float2int_rn(tx);              // round half-to-even
        const bool valid = (ix >= 0) & (ix < NDETC) & (iy >= 0) & (iy < VIEWN);
        const int ixc = min(max(ix, 0), NDETC - 1);
        const int iyc = min(max(iy, 0), VIEWN - 1);
        const float val = valid ? filt[iyc * NDETC + ixc] : 0.0f;
        const float sq  = (float)(t * t * INV);         // U^2, ~1e-7 rel vs host
        acc += val * __builtin_amdgcn_rcpf(sq);         // sq in [0.25,2.3]
    }
    partial[(size_t)c * HWPIX + p] = acc;
}

// ---------------------------------------------------------------------------
// Kernel D: out[p] = D_BETA * sum_c partial[c][p] * mask[p]
// ---------------------------------------------------------------------------
__global__ __launch_bounds__(256) void reduce_kernel(
    const float* __restrict__ partial, const float* __restrict__ mask,
    float* __restrict__ out)
{
    const int p = blockIdx.x * 256 + threadIdx.x;
    const double db = ((3.141592653589793 * 360.0) / 360.0) / 180.0;
    float s = 0.0f;
    #pragma unroll
    for (int c = 0; c < VC; ++c)
        s += partial[(size_t)c * HWPIX + p];
    out[p] = (float)(db * (double)s * (double)mask[p]);
}

extern "C" void kernel_launch(void* const* d_in, const int* in_sizes, int n_in,
                              void* d_out, int out_size, void* d_ws, size_t ws_size,
                              hipStream_t stream)
{
    (void)in_sizes; (void)n_in; (void)out_size; (void)ws_size;
    const float* sino   = (const float*)d_in[0];
    const float* cw     = (const float*)d_in[1];
    const float* rf     = (const float*)d_in[2];
    const float* win    = (const float*)d_in[3];
    const float* grid   = (const float*)d_in[4];
    const float* mask   = (const float*)d_in[6];
    float* out = (float*)d_out;

    // ws layout: g[2048] | filt[360*736] | partial[8*102400] | iy_tab[360] | sbcb[360*2 f64]
    char* ws = (char*)d_ws;
    float*  g       = (float*)(ws);
    float*  filt    = (float*)(ws + 8192);
    float*  partial = (float*)(ws + 8192 + (size_t)VIEWN * NDETC * 4);          // 1,068,032
    int*    iy_tab  = (int*)  (ws + 8192 + (size_t)VIEWN * NDETC * 4
                                  + (size_t)VC * HWPIX * 4);                    // 4,344,832
    double* sbcb    = (double*)(ws + 4346272);                                  // 8-aligned

    build_g_vt_kernel<<<NP2 + 1, 256, 0, stream>>>(rf, win, grid, g, sbcb, iy_tab);
    filter_kernel<<<dim3(VIEWN, 2), 128, 0, stream>>>(sino, cw, g, filt);
    backproject_kernel<<<dim3(HWPIX / 256, VC), 256, 0, stream>>>(sbcb, iy_tab, filt, partial);
    reduce_kernel<<<HWPIX / 256, 256, 0, stream>>>(partial, mask, out);
}

// Round 7
// 61.069 us; speedup vs baseline: 2.2569x; 1.1287x over previous
//
#include <hip/hip_runtime.h>

#define VIEWN 360
#define NDETC 736
#define HWPIX 102400     // 320*320
#define VC    8          // view chunks in backprojection
#define VPC   45         // views per chunk
#define NWORK 66240      // 360*184 conv output-workers (4 outputs each)
#define FBLK  518        // conv blocks: ceil(66240/128)

// ws layout (bytes)
#define OFF_FILT 0                         // 360*736 f32   = 1,059,840
#define OFF_PART 1059840                   // 8*102400 f32  = 3,276,800
#define OFF_DTAB 4336640                   // 2*360 f64     = 5,760
#define OFF_IY   4342400                   // 360 i32

// ---------------------------------------------------------------------------
// Kernel 1: blocks 0..517 — ramp-filter conv; block 518 — per-view tables.
// g is ANALYTIC (== Re(ifft(recon_filter)), verified identical to the DFT g):
//   g[m] = 0.25*(h[m] + h[(2048-m)&2047]),  h[idx]: n=idx-735,
//   h = 1 at n=0, -4/(pi^2 n^2) at odd n, else 0   (DELTA_S=0.5 folded)
// filt[v][d] = sum_k sino[v][k]*cw[k]*g[d+735-k]; 4 outputs/worker, k-range
// split across 2 thread-halves, combined in LDS (value-rounding only).
// ---------------------------------------------------------------------------
__global__ __launch_bounds__(256) void filter_tab_kernel(
    const float* __restrict__ sino, const float* __restrict__ cw,
    const float* __restrict__ grid, char* __restrict__ ws)
{
    const int tid = threadIdx.x;
    if (blockIdx.x == FBLK) {
        double* dtab = (double*)(ws + OFF_DTAB);
        int*    iyt  = (int*)   (ws + OFF_IY);
        for (int v = tid; v < VIEWN; v += 256) {
            const double db   = ((3.141592653589793 * 360.0) / 360.0) / 180.0;
            const double stop = 359.0 * db;           // np.linspace replication
            const double step = stop / 359.0;
            const double beta = (v == 359) ? stop : (double)v * step;
            dtab[2 * v]     = sin(beta);
            dtab[2 * v + 1] = cos(beta);
            const float gy = grid[(size_t)v * HWPIX * 2 + 1];  // tiled per view
            float t = __fadd_rn(gy, 1.f);             // strict f32 == numpy
            t = __fmul_rn(t, 360.f);
            t = __fadd_rn(t, -1.f);
            t = __fmul_rn(t, 0.5f);
            iyt[v] = __float2int_rn(t);               // v=359 -> 360 -> invalid
        }
        return;
    }
    __shared__ __align__(16) float gs[1472];
    __shared__ __align__(16) float ws2[2][NDETC];
    __shared__ __align__(16) float comb[128][4];
    float* filt = (float*)(ws + OFF_FILT);
    const int b = blockIdx.x;
    const int vbase = (b * 128) / 184;
    for (int m = tid; m < 1472; m += 256) {           // analytic ramp kernel
        const int n1 = m - 735;
        const int n2 = ((2048 - m) & 2047) - 735;
        const double h1 = (n1 == 0) ? 1.0 : ((n1 & 1) ? -4.0 / (9.869604401089358 * (double)(n1 * n1)) : 0.0);
        const double h2 = (n2 == 0) ? 1.0 : ((n2 & 1) ? -4.0 / (9.869604401089358 * (double)(n2 * n2)) : 0.0);
        gs[m] = (float)(0.25 * (h1 + h2));
    }
    for (int idx = tid; idx < 2 * NDETC; idx += 256) { // stage <=2 sino rows
        const int vv = idx / NDETC, k = idx % NDETC;
        const int v = vbase + vv;
        if (v < VIEWN) ws2[vv][k] = sino[v * NDETC + k] * cw[k];
    }
    __syncthreads();
    const int o    = b * 128 + (tid & 127);           // output-worker id
    const int half = tid >> 7;                        // k-range half
    float4 acc = make_float4(0.f, 0.f, 0.f, 0.f);
    int v = 0, d = 0;
    if (o < NWORK) {
        v = o / 184;
        d = 4 * (o % 184);
        const float* wsrow = ws2[v - vbase];
        const int kbeg = 368 * half;
        float4 p = *(const float4*)&gs[d + 736 - kbeg];   // win[4..6] seed
        for (int k0 = kbeg; k0 < kbeg + 368; k0 += 4) {
            const float4 c = *(const float4*)&gs[d + 732 - k0]; // 16B-aligned
            const float4 w = *(const float4*)&wsrow[k0];
            acc.x = fmaf(w.x, c.w, acc.x);
            acc.y = fmaf(w.x, p.x, acc.y);
            acc.z = fmaf(w.x, p.y, acc.z);
            acc.w = fmaf(w.x, p.z, acc.w);
            acc.x = fmaf(w.y, c.z, acc.x);
            acc.y = fmaf(w.y, c.w, acc.y);
            acc.z = fmaf(w.y, p.x, acc.z);
            acc.w = fmaf(w.y, p.y, acc.w);
            acc.x = fmaf(w.z, c.y, acc.x);
            acc.y = fmaf(w.z, c.z, acc.y);
            acc.z = fmaf(w.z, c.w, acc.z);
            acc.w = fmaf(w.z, p.x, acc.w);
            acc.x = fmaf(w.w, c.x, acc.x);
            acc.y = fmaf(w.w, c.y, acc.y);
            acc.z = fmaf(w.w, c.z, acc.z);
            acc.w = fmaf(w.w, c.w, acc.w);
            p = c;
        }
    }
    if (half == 1) *(float4*)&comb[tid & 127][0] = acc;
    __syncthreads();
    if (half == 0 && o < NWORK) {
        const float4 bs = *(const float4*)&comb[tid][0];
        acc.x += bs.x; acc.y += bs.y; acc.z += bs.z; acc.w += bs.w;
        *(float4*)&filt[v * NDETC + d] = acc;          // 16B-aligned
    }
}

// ---------------------------------------------------------------------------
// Kernel 2: backprojection — ROUND-4-EXACT f64 math, NO fused reduce.
//   rs = sb*xj - cb*yi ; num = cb*xj + sb*yi ; t = 500 + rs
//   r0 = rcpf(t) + 2 f64 Newton steps ; gxd = (num*CGX)*r0
//   index chain strict f32 (uncontracted) + round-half-even
//   sq = (float)(t*t/250000) ; acc += val * rcpf(sq)
// ---------------------------------------------------------------------------
__global__ __launch_bounds__(256) void bp_kernel(
    char* __restrict__ ws, float* __restrict__ part_out)
{
    const float*  filt = (const float*)(ws + OFF_FILT);
    const double* dtab = (const double*)(ws + OFF_DTAB);
    const int*    iyt  = (const int*)(ws + OFF_IY);
    const int pb = blockIdx.x, c = blockIdx.y;
    const int p  = pb * 256 + threadIdx.x;
    const int j  = p % 320, i = p / 320;
    const double xj = ((double)j - 159.5) * 1.1;    // exact f64 grid coords
    const double yi = ((double)i - 159.5) * 1.1;
    const double CGX = 500.0 / 183.75;
    const double INV = 1.0 / 250000.0;
    float acc = 0.f;
    const int v0 = c * VPC;
    #pragma unroll 3
    for (int v = v0; v < v0 + VPC; ++v) {
        const double sb = dtab[2 * v];
        const double cb = dtab[2 * v + 1];
        const int iy = iyt[v];                        // uniform -> scalar load
        const double rs  = sb * xj - cb * yi;         // r*sin(beta-phi)
        const double num = cb * xj + sb * yi;         // r*cos(beta-phi)
        const double t   = 500.0 + rs;                // 500*U, t in [252,748]
        double r0 = (double)__builtin_amdgcn_rcpf((float)t);
        r0 = r0 * fma(-t, r0, 2.0);                   // Newton 1
        r0 = r0 * fma(-t, r0, 2.0);                   // Newton 2: ~f64 rounding
        const double gxd = (num * CGX) * r0;
        const float  gx  = (float)gxd;
        float tx = __fadd_rn(gx, 1.f);                // strict f32, no FMA
        tx = __fmul_rn(tx, 736.f);
        tx = __fadd_rn(tx, -1.f);
        tx = __fmul_rn(tx, 0.5f);
        const int ix = __float2int_rn(tx);            // round half-to-even
        const bool valid = (ix >= 0) & (ix < NDETC) & (iy >= 0) & (iy < VIEWN);
        const int ixc = min(max(ix, 0), NDETC - 1);
        const int iyc = min(max(iy, 0), VIEWN - 1);
        const float val = valid ? filt[iyc * NDETC + ixc] : 0.f;
        const float sq  = (float)(t * t * INV);       // U^2
        acc += val * __builtin_amdgcn_rcpf(sq);       // sq in [0.25,2.3]
    }
    part_out[(size_t)c * HWPIX + p] = acc;
}

// ---------------------------------------------------------------------------
// Kernel 3: out[p] = D_BETA * sum_c part[c][p] * mask[p]  (c-ascending order)
// Separate launch: the kernel boundary guarantees cross-XCD visibility.
// ---------------------------------------------------------------------------
__global__ __launch_bounds__(256) void reduce_kernel(
    const float* __restrict__ part, const float* __restrict__ mask,
    float* __restrict__ out)
{
    const int p = blockIdx.x * 256 + threadIdx.x;
    const double db = ((3.141592653589793 * 360.0) / 360.0) / 180.0;
    float s = 0.f;
    #pragma unroll
    for (int cc = 0; cc < VC; ++cc)
        s += part[(size_t)cc * HWPIX + p];
    out[p] = (float)(db * (double)s * (double)mask[p]);
}

extern "C" void kernel_launch(void* const* d_in, const int* in_sizes, int n_in,
                              void* d_out, int out_size, void* d_ws, size_t ws_size,
                              hipStream_t stream)
{
    (void)in_sizes; (void)n_in; (void)out_size; (void)ws_size;
    const float* sino = (const float*)d_in[0];
    const float* cw   = (const float*)d_in[1];
    const float* grid = (const float*)d_in[4];
    const float* mask = (const float*)d_in[6];
    float* out = (float*)d_out;
    char*  ws  = (char*)d_ws;
    float* part = (float*)(ws + OFF_PART);

    filter_tab_kernel<<<FBLK + 1, 256, 0, stream>>>(sino, cw, grid, ws);
    bp_kernel<<<dim3(HWPIX / 256, VC), 256, 0, stream>>>(ws, part);
    reduce_kernel<<<HWPIX / 256, 256, 0, stream>>>(part, mask, out);
}